// Round 16
// baseline (182.603 us; speedup 1.0000x reference)
//
#include <hip/hip_runtime.h>

// Problem constants (B=16, T=2048, D=512, A=128)
#define NB 16
#define NT 2048
#define ND 512
#define NA 128
#define EPSV 1e-6f
#define SCALE 0.08838834764831845f  // 128^-0.5
#define NCH 4        // s-chunks in attention
#define SCH 512      // s-chunk length

typedef __bf16 bf16;
typedef __bf16 bf16x4 __attribute__((ext_vector_type(4)));
typedef __bf16 bf16x8 __attribute__((ext_vector_type(8)));
typedef float f32x4 __attribute__((ext_vector_type(4)));
typedef float f32x16 __attribute__((ext_vector_type(16)));

// ---------------------------------------------------------------------------
// Kernel 0: build W^T bf16 [256][512]  (rows 0..127 = Wq cols, 128..255 = Wk)
// ---------------------------------------------------------------------------
__global__ void prep_wt(const float* __restrict__ Wq, const float* __restrict__ Wk,
                        bf16* __restrict__ WT) {
    int n = blockIdx.x;
    const float* W = (n < NA) ? Wq : Wk;
    int col = n & (NA - 1);
    for (int k = threadIdx.x; k < ND; k += blockDim.x)
        WT[(size_t)n * ND + k] = (bf16)W[(size_t)k * NA + col];
}

// ---------------------------------------------------------------------------
// Kernel 1: fused norm + V + QK projection GEMM. 16 rows/block, grid 2048.
// ---------------------------------------------------------------------------
__launch_bounds__(256)
__global__ void norm_proj(const float* __restrict__ x, const float* __restrict__ Wv,
                          const float* __restrict__ bvp, const bf16* __restrict__ WT,
                          const float* __restrict__ bq, const float* __restrict__ bk,
                          bf16* __restrict__ QK, float* __restrict__ Vout) {
    __shared__ bf16 xn[16 * ND];  // 16 KB, XOR-swizzled rows
    const int tid = threadIdx.x;
    const int lane = tid & 63, wv = tid >> 6;
    const int row0 = blockIdx.x * 16;

    float wvv[8];
    float sumw = 0.f;
#pragma unroll
    for (int i = 0; i < 4; ++i) { wvv[i]     = Wv[lane * 4 + i];       sumw += wvv[i]; }
#pragma unroll
    for (int i = 0; i < 4; ++i) { wvv[4 + i] = Wv[256 + lane * 4 + i]; sumw += wvv[4 + i]; }
#pragma unroll
    for (int m = 1; m < 64; m <<= 1) sumw += __shfl_xor(sumw, m);
    const float bvs = bvp[0];

#pragma unroll
    for (int r = 0; r < 4; ++r) {
        const int lrow = wv * 4 + r;
        const int grow = row0 + lrow;
        const float* xr = x + (size_t)grow * ND;
        f32x4 a = *(const f32x4*)(xr + lane * 4);
        f32x4 b = *(const f32x4*)(xr + 256 + lane * 4);
        float s = 0.f, sq = 0.f, dw = 0.f;
#pragma unroll
        for (int i = 0; i < 4; ++i) { s += a[i]; sq += a[i] * a[i]; dw += a[i] * wvv[i]; }
#pragma unroll
        for (int i = 0; i < 4; ++i) { s += b[i]; sq += b[i] * b[i]; dw += b[i] * wvv[4 + i]; }
#pragma unroll
        for (int m = 1; m < 64; m <<= 1) {
            s  += __shfl_xor(s, m);
            sq += __shfl_xor(sq, m);
            dw += __shfl_xor(dw, m);
        }
        const float mu  = s * (1.f / 512.f);
        float var = (sq - 512.f * mu * mu) * (1.f / 511.f);
        var = fmaxf(var, 0.f);
        const float inv = 1.f / (sqrtf(var) + EPSV);
        if (lane == 0) Vout[grow] = (dw - mu * sumw) * inv + bvs;

        const int sw = (lrow & 7) << 4;
        bf16x4 v0, v1;
#pragma unroll
        for (int i = 0; i < 4; ++i) v0[i] = (bf16)((a[i] - mu) * inv);
#pragma unroll
        for (int i = 0; i < 4; ++i) v1[i] = (bf16)((b[i] - mu) * inv);
        *(bf16x4*)((char*)xn + lrow * 1024 + ((lane * 8) ^ sw))       = v0;
        *(bf16x4*)((char*)xn + lrow * 1024 + ((512 + lane * 8) ^ sw)) = v1;
    }
    __syncthreads();

    const int c = lane & 15, g = lane >> 4;
    const int asw = (c & 7) << 4;
    f32x4 acc[4];
#pragma unroll
    for (int i = 0; i < 4; ++i) acc[i] = f32x4{0.f, 0.f, 0.f, 0.f};

    for (int ks = 0; ks < 16; ++ks) {
        const bf16x8 af = *(const bf16x8*)((const char*)xn + c * 1024 +
                                           ((ks * 64 + g * 16) ^ asw));
#pragma unroll
        for (int i = 0; i < 4; ++i) {
            const int n = wv * 64 + i * 16 + c;
            const bf16x8 bfr = *(const bf16x8*)(WT + (size_t)n * ND + ks * 32 + g * 8);
            acc[i] = __builtin_amdgcn_mfma_f32_16x16x32_bf16(af, bfr, acc[i], 0, 0, 0);
        }
    }
#pragma unroll
    for (int i = 0; i < 4; ++i) {
        const int n = wv * 64 + i * 16 + c;
        const float bias = (n < NA) ? bq[n] : bk[n - NA];
#pragma unroll
        for (int j = 0; j < 4; ++j)
            QK[(size_t)(row0 + g * 4 + j) * 256 + n] = (bf16)(acc[i][j] + bias);
    }
}

// ---------------------------------------------------------------------------
// Kernel 2: pass1 — 32x32x16 MFMA. Wave (th,sh) 2x2 grid: each wave owns a
// 32-t x 32-s quadrant per tile -> reads only HALF the K tile from LDS.
// D layout: col=lane&31 (=t), row=(reg&3)+8*(reg>>2)+4*(lane>>5) (=s).
// ---------------------------------------------------------------------------
__launch_bounds__(256)
__global__ void attn_pass1(const bf16* __restrict__ QK, const float* __restrict__ Vg,
                           float* __restrict__ pl, float* __restrict__ pw) {
    __shared__ bf16 Kt[64 * NA];  // 16 KB, XOR-swizzled (row&15)<<4
    __shared__ float redl[4][32], redw[4][32];
    const int tid = threadIdx.x;
    const int lane = tid & 63, w = tid >> 6;
    const int b = blockIdx.z, t0 = blockIdx.x * 64, sc = blockIdx.y;
    const int j = lane & 31, h = lane >> 5;     // D col (t), k-half
    const int th = w >> 1, sh = w & 1;          // wave quadrant
    const int tcol = t0 + th * 32 + j;

    // Q B-fragments: col=lane&31=t, k = ks16*16 + h*8 + e
    bf16x8 qf[8];
    const bf16* qrow = QK + (size_t)(b * NT + tcol) * 256;
#pragma unroll
    for (int ks = 0; ks < 8; ++ks) qf[ks] = *(const bf16x8*)(qrow + ks * 16 + h * 8);

    const int srow = tid >> 4, scc = tid & 15;
    const bf16* kbase = QK + (size_t)(b * NT + sc * SCH + srow) * 256 + NA + scc * 8;
    bf16* kdst = (bf16*)((char*)Kt + srow * 256 + ((scc * 16) ^ (srow << 4)));
    bf16x8 sreg[4];

    // prologue: stage tile 0
#pragma unroll
    for (int i = 0; i < 4; ++i)
        sreg[i] = *(const bf16x8*)(kbase + (size_t)(i * 16) * 256);
#pragma unroll
    for (int i = 0; i < 4; ++i)
        *(bf16x8*)((char*)kdst + i * 16 * 256) = sreg[i];
    __syncthreads();

    const float* vbase = Vg + b * NT + sc * SCH;
    const int rr = sh * 32 + j;                 // A row (s) for this lane
    const int rsw = (rr & 15) << 4;
    const char* abase = (const char*)Kt + rr * 256;
    float l_loc = 0.f, w_loc = 0.f;

    for (int tt = 0; tt < SCH / 64; ++tt) {
        if (tt + 1 < SCH / 64) {  // issue next-tile loads BEFORE compute
#pragma unroll
            for (int i = 0; i < 4; ++i)
                sreg[i] = *(const bf16x8*)(kbase + (size_t)((tt + 1) * 64 + i * 16) * 256);
        }

        f32x16 acc = (f32x16)(0.0f);
#pragma unroll
        for (int ks = 0; ks < 8; ++ks) {
            const bf16x8 af = *(const bf16x8*)(abase + ((ks * 32 + h * 16) ^ rsw));
            acc = __builtin_amdgcn_mfma_f32_32x32x16_bf16(af, qf[ks], acc, 0, 0, 0);
        }
#pragma unroll
        for (int q = 0; q < 4; ++q) {
            const f32x4 vv = *(const f32x4*)(vbase + tt * 64 + sh * 32 + 8 * q + 4 * h);
#pragma unroll
            for (int r = 0; r < 4; ++r) {
                const float p = __expf(acc[4 * q + r] * SCALE);
                l_loc += p;
                w_loc += p * vv[r];
            }
        }

        if (tt + 1 < SCH / 64) {
            __syncthreads();  // waves done reading Kt; drain covered by compute
#pragma unroll
            for (int i = 0; i < 4; ++i)
                *(bf16x8*)((char*)kdst + i * 16 * 256) = sreg[i];
            __syncthreads();  // Kt visible
        }
    }

    // reduce over h (lane ^ 32 shares t-col), then over sh via LDS
    l_loc += __shfl_xor(l_loc, 32);
    w_loc += __shfl_xor(w_loc, 32);
    if (h == 0) {
        redl[w][j] = l_loc;
        redw[w][j] = w_loc;
    }
    __syncthreads();
    if (tid < 64) {
        const int tth = tid >> 5, tj = tid & 31;
        const float L = redl[tth * 2][tj] + redl[tth * 2 + 1][tj];
        const float W = redw[tth * 2][tj] + redw[tth * 2 + 1][tj];
        const int idx = sc * (NB * NT) + b * NT + t0 + tid;
        pl[idx] = L;
        pw[idx] = W;
    }
}

// ---------------------------------------------------------------------------
// Kernel 3: pass2 — 32x32x16 MFMA; folds partials per-thread, writes out_w
// (sc==0), recomputes scores, writes normalized w_att (f32x4 along s).
// ---------------------------------------------------------------------------
__launch_bounds__(256)
__global__ void attn_pass2(const bf16* __restrict__ QK, const float* __restrict__ pl,
                           const float* __restrict__ pw, float* __restrict__ out_w,
                           float* __restrict__ out_att) {
    __shared__ bf16 Kt[64 * NA];
    const int tid = threadIdx.x;
    const int lane = tid & 63, w = tid >> 6;
    const int b = blockIdx.z, t0 = blockIdx.x * 64, sc = blockIdx.y;
    const int j = lane & 31, h = lane >> 5;
    const int th = w >> 1, sh = w & 1;
    const int tcol = t0 + th * 32 + j;

    bf16x8 qf[8];
    const bf16* qrow = QK + (size_t)(b * NT + tcol) * 256;
#pragma unroll
    for (int ks = 0; ks < 8; ++ks) qf[ks] = *(const bf16x8*)(qrow + ks * 16 + h * 8);

    // fold partials (L2-hot)
    float L = 0.f, W = 0.f;
#pragma unroll
    for (int ch = 0; ch < NCH; ++ch) {
        L += pl[ch * (NB * NT) + b * NT + tcol];
        W += pw[ch * (NB * NT) + b * NT + tcol];
    }
    const float lrow = 1.f / L;
    if (sc == 0 && sh == 0 && h == 0) out_w[b * NT + tcol] = W * lrow;

    const int srow = tid >> 4, scc = tid & 15;
    const bf16* kbase = QK + (size_t)(b * NT + sc * SCH + srow) * 256 + NA + scc * 8;
    bf16* kdst = (bf16*)((char*)Kt + srow * 256 + ((scc * 16) ^ (srow << 4)));
    bf16x8 sreg[4];

#pragma unroll
    for (int i = 0; i < 4; ++i)
        sreg[i] = *(const bf16x8*)(kbase + (size_t)(i * 16) * 256);
#pragma unroll
    for (int i = 0; i < 4; ++i)
        *(bf16x8*)((char*)kdst + i * 16 * 256) = sreg[i];
    __syncthreads();

    const int rr = sh * 32 + j;
    const int rsw = (rr & 15) << 4;
    const char* abase = (const char*)Kt + rr * 256;
    float* orow = out_att + (size_t)(b * NT + tcol) * NT;

    for (int tt = 0; tt < SCH / 64; ++tt) {
        if (tt + 1 < SCH / 64) {
#pragma unroll
            for (int i = 0; i < 4; ++i)
                sreg[i] = *(const bf16x8*)(kbase + (size_t)((tt + 1) * 64 + i * 16) * 256);
        }

        f32x16 acc = (f32x16)(0.0f);
#pragma unroll
        for (int ks = 0; ks < 8; ++ks) {
            const bf16x8 af = *(const bf16x8*)(abase + ((ks * 32 + h * 16) ^ rsw));
            acc = __builtin_amdgcn_mfma_f32_32x32x16_bf16(af, qf[ks], acc, 0, 0, 0);
        }
        const int s0 = sc * SCH + tt * 64 + sh * 32 + 4 * h;
#pragma unroll
        for (int q = 0; q < 4; ++q) {
            f32x4 w4;
#pragma unroll
            for (int r = 0; r < 4; ++r)
                w4[r] = __expf(acc[4 * q + r] * SCALE) * lrow;
            *(f32x4*)(orow + s0 + 8 * q) = w4;
        }

        if (tt + 1 < SCH / 64) {
            __syncthreads();
#pragma unroll
            for (int i = 0; i < 4; ++i)
                *(bf16x8*)((char*)kdst + i * 16 * 256) = sreg[i];
            __syncthreads();
        }
    }
}

// ---------------------------------------------------------------------------
extern "C" void kernel_launch(void* const* d_in, const int* in_sizes, int n_in,
                              void* d_out, int out_size, void* d_ws, size_t ws_size,
                              hipStream_t stream) {
    const float* x  = (const float*)d_in[0];
    const float* Wq = (const float*)d_in[1];
    const float* bq = (const float*)d_in[2];
    const float* Wk = (const float*)d_in[3];
    const float* bk = (const float*)d_in[4];
    const float* Wv = (const float*)d_in[5];
    const float* bv = (const float*)d_in[6];

    float* out_w   = (float*)d_out;            // [B,T,1] = 32768
    float* out_att = (float*)d_out + NB * NT;  // [B,T,T]

    char* ws = (char*)d_ws;
    bf16*  WT = (bf16*)ws;                       // 262144 B
    float* V  = (float*)(ws + 262144);           // 131072 B
    bf16*  QK = (bf16*)(ws + 393216);            // 16 MB
    float* pl = (float*)(ws + 17170432);         // 512 KB
    float* pw = (float*)(ws + 17694720);         // 512 KB

    prep_wt<<<dim3(256), dim3(256), 0, stream>>>(Wq, Wk, WT);
    norm_proj<<<dim3((NB * NT) / 16), dim3(256), 0, stream>>>(x, Wv, bv, WT, bq, bk, QK, V);
    attn_pass1<<<dim3(NT / 64, NCH, NB), dim3(256), 0, stream>>>(QK, V, pl, pw);
    attn_pass2<<<dim3(NT / 64, NCH, NB), dim3(256), 0, stream>>>(QK, pl, pw, out_w, out_att);
}

// Round 17
// 176.940 us; speedup vs baseline: 1.0320x; 1.0320x over previous
//
#include <hip/hip_runtime.h>

// Problem constants (B=16, T=2048, D=512, A=128)
#define NB 16
#define NT 2048
#define ND 512
#define NA 128
#define EPSV 1e-6f
#define SCALE 0.08838834764831845f  // 128^-0.5
#define NCH 4        // s-chunks in attention
#define SCH 512      // s-chunk length

typedef __bf16 bf16;
typedef __bf16 bf16x4 __attribute__((ext_vector_type(4)));
typedef __bf16 bf16x8 __attribute__((ext_vector_type(8)));
typedef float f32x4 __attribute__((ext_vector_type(4)));

// ---------------------------------------------------------------------------
// Kernel 0: build W^T bf16 [256][512]  (rows 0..127 = Wq cols, 128..255 = Wk)
// ---------------------------------------------------------------------------
__global__ void prep_wt(const float* __restrict__ Wq, const float* __restrict__ Wk,
                        bf16* __restrict__ WT) {
    int n = blockIdx.x;
    const float* W = (n < NA) ? Wq : Wk;
    int col = n & (NA - 1);
    for (int k = threadIdx.x; k < ND; k += blockDim.x)
        WT[(size_t)n * ND + k] = (bf16)W[(size_t)k * NA + col];
}

// ---------------------------------------------------------------------------
// Kernel 1: fused norm + V + QK projection GEMM. 16 rows/block, grid 2048.
// ---------------------------------------------------------------------------
__launch_bounds__(256)
__global__ void norm_proj(const float* __restrict__ x, const float* __restrict__ Wv,
                          const float* __restrict__ bvp, const bf16* __restrict__ WT,
                          const float* __restrict__ bq, const float* __restrict__ bk,
                          bf16* __restrict__ QK, float* __restrict__ Vout) {
    __shared__ bf16 xn[16 * ND];  // 16 KB, XOR-swizzled rows
    const int tid = threadIdx.x;
    const int lane = tid & 63, wv = tid >> 6;
    const int row0 = blockIdx.x * 16;

    float wvv[8];
    float sumw = 0.f;
#pragma unroll
    for (int i = 0; i < 4; ++i) { wvv[i]     = Wv[lane * 4 + i];       sumw += wvv[i]; }
#pragma unroll
    for (int i = 0; i < 4; ++i) { wvv[4 + i] = Wv[256 + lane * 4 + i]; sumw += wvv[4 + i]; }
#pragma unroll
    for (int m = 1; m < 64; m <<= 1) sumw += __shfl_xor(sumw, m);
    const float bvs = bvp[0];

#pragma unroll
    for (int r = 0; r < 4; ++r) {
        const int lrow = wv * 4 + r;
        const int grow = row0 + lrow;
        const float* xr = x + (size_t)grow * ND;
        f32x4 a = *(const f32x4*)(xr + lane * 4);
        f32x4 b = *(const f32x4*)(xr + 256 + lane * 4);
        float s = 0.f, sq = 0.f, dw = 0.f;
#pragma unroll
        for (int i = 0; i < 4; ++i) { s += a[i]; sq += a[i] * a[i]; dw += a[i] * wvv[i]; }
#pragma unroll
        for (int i = 0; i < 4; ++i) { s += b[i]; sq += b[i] * b[i]; dw += b[i] * wvv[4 + i]; }
#pragma unroll
        for (int m = 1; m < 64; m <<= 1) {
            s  += __shfl_xor(s, m);
            sq += __shfl_xor(sq, m);
            dw += __shfl_xor(dw, m);
        }
        const float mu  = s * (1.f / 512.f);
        float var = (sq - 512.f * mu * mu) * (1.f / 511.f);
        var = fmaxf(var, 0.f);
        const float inv = 1.f / (sqrtf(var) + EPSV);
        if (lane == 0) Vout[grow] = (dw - mu * sumw) * inv + bvs;

        const int sw = (lrow & 7) << 4;
        bf16x4 v0, v1;
#pragma unroll
        for (int i = 0; i < 4; ++i) v0[i] = (bf16)((a[i] - mu) * inv);
#pragma unroll
        for (int i = 0; i < 4; ++i) v1[i] = (bf16)((b[i] - mu) * inv);
        *(bf16x4*)((char*)xn + lrow * 1024 + ((lane * 8) ^ sw))       = v0;
        *(bf16x4*)((char*)xn + lrow * 1024 + ((512 + lane * 8) ^ sw)) = v1;
    }
    __syncthreads();

    const int c = lane & 15, g = lane >> 4;
    const int asw = (c & 7) << 4;
    f32x4 acc[4];
#pragma unroll
    for (int i = 0; i < 4; ++i) acc[i] = f32x4{0.f, 0.f, 0.f, 0.f};

    for (int ks = 0; ks < 16; ++ks) {
        const bf16x8 af = *(const bf16x8*)((const char*)xn + c * 1024 +
                                           ((ks * 64 + g * 16) ^ asw));
#pragma unroll
        for (int i = 0; i < 4; ++i) {
            const int n = wv * 64 + i * 16 + c;
            const bf16x8 bfr = *(const bf16x8*)(WT + (size_t)n * ND + ks * 32 + g * 8);
            acc[i] = __builtin_amdgcn_mfma_f32_16x16x32_bf16(af, bfr, acc[i], 0, 0, 0);
        }
    }
#pragma unroll
    for (int i = 0; i < 4; ++i) {
        const int n = wv * 64 + i * 16 + c;
        const float bias = (n < NA) ? bq[n] : bk[n - NA];
#pragma unroll
        for (int j = 0; j < 4; ++j)
            QK[(size_t)(row0 + g * 4 + j) * 256 + n] = (bf16)(acc[i][j] + bias);
    }
}

// ---------------------------------------------------------------------------
// Kernel 2: pass1 — 2x2 quadrant split, 16x16 MFMA. Wave (th,sh) owns a
// 32-t x 32-s quadrant: 8 ds_read/wave/tile (half the tile) vs R15's 16.
// ---------------------------------------------------------------------------
__launch_bounds__(256)
__global__ void attn_pass1(const bf16* __restrict__ QK, const float* __restrict__ Vg,
                           float* __restrict__ pl, float* __restrict__ pw) {
    __shared__ bf16 Kt[64 * NA];  // 16 KB, XOR-swizzled
    __shared__ float redl[4][32], redw[4][32];
    const int tid = threadIdx.x;
    const int lane = tid & 63, w = tid >> 6;
    const int b = blockIdx.z, t0 = blockIdx.x * 64, sc = blockIdx.y;
    const int c = lane & 15, g = lane >> 4;
    const int th = w >> 1, sh = w & 1;

    // Q B-fragments for the wave's 32 t-rows (2 tg x 16)
    bf16x8 qf[2][4];
#pragma unroll
    for (int tg = 0; tg < 2; ++tg) {
        const bf16* qrow = QK + (size_t)(b * NT + t0 + th * 32 + tg * 16 + c) * 256;
#pragma unroll
        for (int ks = 0; ks < 4; ++ks)
            qf[tg][ks] = *(const bf16x8*)(qrow + ks * 32 + g * 8);
    }

    const int srow = tid >> 4, scc = tid & 15;
    const bf16* kbase = QK + (size_t)(b * NT + sc * SCH + srow) * 256 + NA + scc * 8;
    bf16* kdst = (bf16*)((char*)Kt + srow * 256 + ((scc * 16) ^ ((srow & 7) << 4)));
    bf16x8 sreg[4];

    // prologue: stage tile 0
#pragma unroll
    for (int i = 0; i < 4; ++i)
        sreg[i] = *(const bf16x8*)(kbase + (size_t)(i * 16) * 256);
#pragma unroll
    for (int i = 0; i < 4; ++i)
        *(bf16x8*)((char*)kdst + i * 16 * 256) = sreg[i];
    __syncthreads();

    const float* vbase = Vg + b * NT + sc * SCH;
    float l_loc[2] = {0.f, 0.f}, w_loc[2] = {0.f, 0.f};

    for (int tt = 0; tt < SCH / 64; ++tt) {
        if (tt + 1 < SCH / 64) {  // issue next-tile loads BEFORE compute
#pragma unroll
            for (int i = 0; i < 4; ++i)
                sreg[i] = *(const bf16x8*)(kbase + (size_t)((tt + 1) * 64 + i * 16) * 256);
        }

        // A-frags for this wave's s-half (2 sg x 16 rows)
        bf16x8 af[2][4];
#pragma unroll
        for (int sg = 0; sg < 2; ++sg) {
            const int rr = sh * 32 + sg * 16 + c;
            const int rsw = (rr & 7) << 4;
            const char* abase = (const char*)Kt + rr * 256;
#pragma unroll
            for (int ks = 0; ks < 4; ++ks)
                af[sg][ks] = *(const bf16x8*)(abase + ((ks * 64 + g * 16) ^ rsw));
        }

#pragma unroll
        for (int tg = 0; tg < 2; ++tg) {
#pragma unroll
            for (int sg = 0; sg < 2; ++sg) {
                f32x4 acc = f32x4{0.f, 0.f, 0.f, 0.f};
#pragma unroll
                for (int ks = 0; ks < 4; ++ks)
                    acc = __builtin_amdgcn_mfma_f32_16x16x32_bf16(af[sg][ks], qf[tg][ks],
                                                                  acc, 0, 0, 0);
                const f32x4 vv = *(const f32x4*)(vbase + tt * 64 + sh * 32 + sg * 16 + g * 4);
#pragma unroll
                for (int jj = 0; jj < 4; ++jj) {
                    const float p = __expf(acc[jj] * SCALE);
                    l_loc[tg] += p;
                    w_loc[tg] += p * vv[jj];
                }
            }
        }

        if (tt + 1 < SCH / 64) {
            __syncthreads();  // waves done reading Kt; drain covered by compute
#pragma unroll
            for (int i = 0; i < 4; ++i)
                *(bf16x8*)((char*)kdst + i * 16 * 256) = sreg[i];
            __syncthreads();  // Kt visible
        }
    }

    // reduce over g (shfl), then over sh (LDS)
#pragma unroll
    for (int tg = 0; tg < 2; ++tg) {
#pragma unroll
        for (int mask = 16; mask <= 32; mask <<= 1) {
            l_loc[tg] += __shfl_xor(l_loc[tg], mask);
            w_loc[tg] += __shfl_xor(w_loc[tg], mask);
        }
    }
    if (g == 0) {
#pragma unroll
        for (int tg = 0; tg < 2; ++tg) {
            redl[w][tg * 16 + c] = l_loc[tg];
            redw[w][tg * 16 + c] = w_loc[tg];
        }
    }
    __syncthreads();
    if (tid < 64) {
        const int th2 = tid >> 5, u = tid & 31;
        const float L = redl[th2 * 2][u] + redl[th2 * 2 + 1][u];
        const float W = redw[th2 * 2][u] + redw[th2 * 2 + 1][u];
        const int idx = sc * (NB * NT) + b * NT + t0 + tid;
        pl[idx] = L;
        pw[idx] = W;
    }
}

// ---------------------------------------------------------------------------
// Kernel 3: pass2 — same quadrant split; folds partials, writes out_w (sc==0,
// sh==0), recomputes scores, R15-style stores (16 rows x 64 B).
// ---------------------------------------------------------------------------
__launch_bounds__(256)
__global__ void attn_pass2(const bf16* __restrict__ QK, const float* __restrict__ pl,
                           const float* __restrict__ pw, float* __restrict__ out_w,
                           float* __restrict__ out_att) {
    __shared__ bf16 Kt[64 * NA];
    const int tid = threadIdx.x;
    const int lane = tid & 63, w = tid >> 6;
    const int b = blockIdx.z, t0 = blockIdx.x * 64, sc = blockIdx.y;
    const int c = lane & 15, g = lane >> 4;
    const int th = w >> 1, sh = w & 1;

    bf16x8 qf[2][4];
    float lrow[2];
#pragma unroll
    for (int tg = 0; tg < 2; ++tg) {
        const int trow = t0 + th * 32 + tg * 16 + c;
        const bf16* qrow = QK + (size_t)(b * NT + trow) * 256;
#pragma unroll
        for (int ks = 0; ks < 4; ++ks)
            qf[tg][ks] = *(const bf16x8*)(qrow + ks * 32 + g * 8);
        float L = 0.f, W = 0.f;
#pragma unroll
        for (int ch = 0; ch < NCH; ++ch) {
            L += pl[ch * (NB * NT) + b * NT + trow];
            W += pw[ch * (NB * NT) + b * NT + trow];
        }
        lrow[tg] = 1.f / L;
        if (sc == 0 && sh == 0 && g == 0) out_w[b * NT + trow] = W * lrow[tg];
    }

    const int srow = tid >> 4, scc = tid & 15;
    const bf16* kbase = QK + (size_t)(b * NT + sc * SCH + srow) * 256 + NA + scc * 8;
    bf16* kdst = (bf16*)((char*)Kt + srow * 256 + ((scc * 16) ^ ((srow & 7) << 4)));
    bf16x8 sreg[4];

#pragma unroll
    for (int i = 0; i < 4; ++i)
        sreg[i] = *(const bf16x8*)(kbase + (size_t)(i * 16) * 256);
#pragma unroll
    for (int i = 0; i < 4; ++i)
        *(bf16x8*)((char*)kdst + i * 16 * 256) = sreg[i];
    __syncthreads();

    for (int tt = 0; tt < SCH / 64; ++tt) {
        if (tt + 1 < SCH / 64) {  // issue next-tile loads BEFORE compute
#pragma unroll
            for (int i = 0; i < 4; ++i)
                sreg[i] = *(const bf16x8*)(kbase + (size_t)((tt + 1) * 64 + i * 16) * 256);
        }

        bf16x8 af[2][4];
#pragma unroll
        for (int sg = 0; sg < 2; ++sg) {
            const int rr = sh * 32 + sg * 16 + c;
            const int rsw = (rr & 7) << 4;
            const char* abase = (const char*)Kt + rr * 256;
#pragma unroll
            for (int ks = 0; ks < 4; ++ks)
                af[sg][ks] = *(const bf16x8*)(abase + ((ks * 64 + g * 16) ^ rsw));
        }

#pragma unroll
        for (int tg = 0; tg < 2; ++tg) {
            float* orow = out_att + (size_t)(b * NT + t0 + th * 32 + tg * 16 + c) * NT;
#pragma unroll
            for (int sg = 0; sg < 2; ++sg) {
                f32x4 acc = f32x4{0.f, 0.f, 0.f, 0.f};
#pragma unroll
                for (int ks = 0; ks < 4; ++ks)
                    acc = __builtin_amdgcn_mfma_f32_16x16x32_bf16(af[sg][ks], qf[tg][ks],
                                                                  acc, 0, 0, 0);
                f32x4 w4;
#pragma unroll
                for (int jj = 0; jj < 4; ++jj)
                    w4[jj] = __expf(acc[jj] * SCALE) * lrow[tg];
                *(f32x4*)(orow + sc * SCH + tt * 64 + sh * 32 + sg * 16 + g * 4) = w4;
            }
        }

        if (tt + 1 < SCH / 64) {
            __syncthreads();
#pragma unroll
            for (int i = 0; i < 4; ++i)
                *(bf16x8*)((char*)kdst + i * 16 * 256) = sreg[i];
            __syncthreads();
        }
    }
}

// ---------------------------------------------------------------------------
extern "C" void kernel_launch(void* const* d_in, const int* in_sizes, int n_in,
                              void* d_out, int out_size, void* d_ws, size_t ws_size,
                              hipStream_t stream) {
    const float* x  = (const float*)d_in[0];
    const float* Wq = (const float*)d_in[1];
    const float* bq = (const float*)d_in[2];
    const float* Wk = (const float*)d_in[3];
    const float* bk = (const float*)d_in[4];
    const float* Wv = (const float*)d_in[5];
    const float* bv = (const float*)d_in[6];

    float* out_w   = (float*)d_out;            // [B,T,1] = 32768
    float* out_att = (float*)d_out + NB * NT;  // [B,T,T]

    char* ws = (char*)d_ws;
    bf16*  WT = (bf16*)ws;                       // 262144 B
    float* V  = (float*)(ws + 262144);           // 131072 B
    bf16*  QK = (bf16*)(ws + 393216);            // 16 MB
    float* pl = (float*)(ws + 17170432);         // 512 KB
    float* pw = (float*)(ws + 17694720);         // 512 KB

    prep_wt<<<dim3(256), dim3(256), 0, stream>>>(Wq, Wk, WT);
    norm_proj<<<dim3((NB * NT) / 16), dim3(256), 0, stream>>>(x, Wv, bv, WT, bq, bk, QK, V);
    attn_pass1<<<dim3(NT / 64, NCH, NB), dim3(256), 0, stream>>>(QK, V, pl, pw);
    attn_pass2<<<dim3(NT / 64, NCH, NB), dim3(256), 0, stream>>>(QK, pl, pw, out_w, out_att);
}

// Round 18
// 176.391 us; speedup vs baseline: 1.0352x; 1.0031x over previous
//
#include <hip/hip_runtime.h>

// Problem constants (B=16, T=2048, D=512, A=128)
#define NB 16
#define NT 2048
#define ND 512
#define NA 128
#define EPSV 1e-6f
#define SCALE 0.08838834764831845f  // 128^-0.5
#define NCH 4        // s-chunks in attention
#define SCH 512      // s-chunk length
#define TR 32        // K-tile rows (dbuf: 2 x 8 KB keeps 8 blocks/CU)

typedef __bf16 bf16;
typedef __bf16 bf16x4 __attribute__((ext_vector_type(4)));
typedef __bf16 bf16x8 __attribute__((ext_vector_type(8)));
typedef float f32x4 __attribute__((ext_vector_type(4)));

__device__ __forceinline__ void gll16(const void* g, void* l) {
    __builtin_amdgcn_global_load_lds(
        (const __attribute__((address_space(1))) void*)g,
        (__attribute__((address_space(3))) void*)l, 16, 0, 0);
}

// ---------------------------------------------------------------------------
// Kernel 0: build W^T bf16 [256][512]  (rows 0..127 = Wq cols, 128..255 = Wk)
// ---------------------------------------------------------------------------
__global__ void prep_wt(const float* __restrict__ Wq, const float* __restrict__ Wk,
                        bf16* __restrict__ WT) {
    int n = blockIdx.x;
    const float* W = (n < NA) ? Wq : Wk;
    int col = n & (NA - 1);
    for (int k = threadIdx.x; k < ND; k += blockDim.x)
        WT[(size_t)n * ND + k] = (bf16)W[(size_t)k * NA + col];
}

// ---------------------------------------------------------------------------
// Kernel 1: fused norm + V + QK projection GEMM. 16 rows/block, grid 2048.
// ---------------------------------------------------------------------------
__launch_bounds__(256)
__global__ void norm_proj(const float* __restrict__ x, const float* __restrict__ Wv,
                          const float* __restrict__ bvp, const bf16* __restrict__ WT,
                          const float* __restrict__ bq, const float* __restrict__ bk,
                          bf16* __restrict__ QK, float* __restrict__ Vout) {
    __shared__ bf16 xn[16 * ND];  // 16 KB, XOR-swizzled rows
    const int tid = threadIdx.x;
    const int lane = tid & 63, wv = tid >> 6;
    const int row0 = blockIdx.x * 16;

    float wvv[8];
    float sumw = 0.f;
#pragma unroll
    for (int i = 0; i < 4; ++i) { wvv[i]     = Wv[lane * 4 + i];       sumw += wvv[i]; }
#pragma unroll
    for (int i = 0; i < 4; ++i) { wvv[4 + i] = Wv[256 + lane * 4 + i]; sumw += wvv[4 + i]; }
#pragma unroll
    for (int m = 1; m < 64; m <<= 1) sumw += __shfl_xor(sumw, m);
    const float bvs = bvp[0];

#pragma unroll
    for (int r = 0; r < 4; ++r) {
        const int lrow = wv * 4 + r;
        const int grow = row0 + lrow;
        const float* xr = x + (size_t)grow * ND;
        f32x4 a = *(const f32x4*)(xr + lane * 4);
        f32x4 b = *(const f32x4*)(xr + 256 + lane * 4);
        float s = 0.f, sq = 0.f, dw = 0.f;
#pragma unroll
        for (int i = 0; i < 4; ++i) { s += a[i]; sq += a[i] * a[i]; dw += a[i] * wvv[i]; }
#pragma unroll
        for (int i = 0; i < 4; ++i) { s += b[i]; sq += b[i] * b[i]; dw += b[i] * wvv[4 + i]; }
#pragma unroll
        for (int m = 1; m < 64; m <<= 1) {
            s  += __shfl_xor(s, m);
            sq += __shfl_xor(sq, m);
            dw += __shfl_xor(dw, m);
        }
        const float mu  = s * (1.f / 512.f);
        float var = (sq - 512.f * mu * mu) * (1.f / 511.f);
        var = fmaxf(var, 0.f);
        const float inv = 1.f / (sqrtf(var) + EPSV);
        if (lane == 0) Vout[grow] = (dw - mu * sumw) * inv + bvs;

        const int sw = (lrow & 7) << 4;
        bf16x4 v0, v1;
#pragma unroll
        for (int i = 0; i < 4; ++i) v0[i] = (bf16)((a[i] - mu) * inv);
#pragma unroll
        for (int i = 0; i < 4; ++i) v1[i] = (bf16)((b[i] - mu) * inv);
        *(bf16x4*)((char*)xn + lrow * 1024 + ((lane * 8) ^ sw))       = v0;
        *(bf16x4*)((char*)xn + lrow * 1024 + ((512 + lane * 8) ^ sw)) = v1;
    }
    __syncthreads();

    const int c = lane & 15, g = lane >> 4;
    const int asw = (c & 7) << 4;
    f32x4 acc[4];
#pragma unroll
    for (int i = 0; i < 4; ++i) acc[i] = f32x4{0.f, 0.f, 0.f, 0.f};

    for (int ks = 0; ks < 16; ++ks) {
        const bf16x8 af = *(const bf16x8*)((const char*)xn + c * 1024 +
                                           ((ks * 64 + g * 16) ^ asw));
#pragma unroll
        for (int i = 0; i < 4; ++i) {
            const int n = wv * 64 + i * 16 + c;
            const bf16x8 bfr = *(const bf16x8*)(WT + (size_t)n * ND + ks * 32 + g * 8);
            acc[i] = __builtin_amdgcn_mfma_f32_16x16x32_bf16(af, bfr, acc[i], 0, 0, 0);
        }
    }
#pragma unroll
    for (int i = 0; i < 4; ++i) {
        const int n = wv * 64 + i * 16 + c;
        const float bias = (n < NA) ? bq[n] : bk[n - NA];
#pragma unroll
        for (int j = 0; j < 4; ++j)
            QK[(size_t)(row0 + g * 4 + j) * 256 + n] = (bf16)(acc[i][j] + bias);
    }
}

// ---------------------------------------------------------------------------
// Kernel 2: pass1 — per-chunk sums l, w. global_load_lds staging (width 16),
// linear LDS dest + inverse-swizzled global source; 32-row K tiles, dbuf,
// ONE barrier per tile. Otherwise R15.
// ---------------------------------------------------------------------------
__launch_bounds__(256)
__global__ void attn_pass1(const bf16* __restrict__ QK, const float* __restrict__ Vg,
                           float* __restrict__ pl, float* __restrict__ pw) {
    __shared__ bf16 Kt[2][TR * NA];  // 2 x 8 KB
    const int tid = threadIdx.x;
    const int lane = tid & 63, w = tid >> 6;
    const int b = blockIdx.z, t0 = blockIdx.x * 64, sc = blockIdx.y;
    const int c = lane & 15, g = lane >> 4;
    const int trow = t0 + w * 16 + c;

    bf16x8 qf[4];
    const bf16* qrow = QK + (size_t)(b * NT + trow) * 256;
#pragma unroll
    for (int ks = 0; ks < 4; ++ks) qf[ks] = *(const bf16x8*)(qrow + ks * 32 + g * 8);

    // staging map: wave w, issue i covers tile rows (w*2+i)*4 + (lane>>4),
    // col chunk cc = lane&15; global source column pre-swizzled (involution).
    const int sr0 = w * 2;                       // row group base /4
    const int lr = lane >> 4, cc = lane & 15;    // lane row-in-group, col chunk
    const bf16* kch = QK + (size_t)(b * NT + sc * SCH) * 256 + NA;

    // prologue: stage tile 0 into buf 0
#pragma unroll
    for (int i = 0; i < 2; ++i) {
        const int r = (sr0 + i) * 4 + lr;
        gll16(kch + (size_t)r * 256 + ((cc ^ (r & 7)) * 8),
              (char*)Kt[0] + (sr0 + i) * 1024);
    }
    __syncthreads();  // drains vmcnt -> tile 0 resident

    const float* vbase = Vg + b * NT + sc * SCH;
    float l_loc = 0.f, w_loc = 0.f;

    for (int tt = 0; tt < SCH / TR; ++tt) {
        if (tt + 1 < SCH / TR) {  // async prefetch next tile into other buf
#pragma unroll
            for (int i = 0; i < 2; ++i) {
                const int r = (sr0 + i) * 4 + lr;
                gll16(kch + (size_t)((tt + 1) * TR + r) * 256 + ((cc ^ (r & 7)) * 8),
                      (char*)Kt[(tt + 1) & 1] + (sr0 + i) * 1024);
            }
        }

        const char* kt = (const char*)Kt[tt & 1];
#pragma unroll
        for (int ns = 0; ns < 2; ++ns) {
            f32x4 acc = f32x4{0.f, 0.f, 0.f, 0.f};
            const int rr = ns * 16 + c;
            const int rsw = (rr & 7) << 4;
#pragma unroll
            for (int ks = 0; ks < 4; ++ks) {
                const bf16x8 afr = *(const bf16x8*)(kt + rr * 256 +
                                                    ((ks * 64 + g * 16) ^ rsw));
                acc = __builtin_amdgcn_mfma_f32_16x16x32_bf16(afr, qf[ks], acc, 0, 0, 0);
            }
            const f32x4 vv = *(const f32x4*)(vbase + tt * TR + ns * 16 + g * 4);
#pragma unroll
            for (int jj = 0; jj < 4; ++jj) {
                const float p = __expf(acc[jj] * SCALE);
                l_loc += p;
                w_loc += p * vv[jj];
            }
        }
        __syncthreads();  // vmcnt drain covered by the compute above
    }

#pragma unroll
    for (int mask = 16; mask <= 32; mask <<= 1) {
        l_loc += __shfl_xor(l_loc, mask);
        w_loc += __shfl_xor(w_loc, mask);
    }
    if (g == 0) {
        const int idx = sc * (NB * NT) + b * NT + trow;
        pl[idx] = l_loc;
        pw[idx] = w_loc;
    }
}

// ---------------------------------------------------------------------------
// Kernel 3: pass2 — folds partials per-thread, writes out_w (sc==0),
// recomputes scores, writes normalized w_att. Same gll staging.
// ---------------------------------------------------------------------------
__launch_bounds__(256)
__global__ void attn_pass2(const bf16* __restrict__ QK, const float* __restrict__ pl,
                           const float* __restrict__ pw, float* __restrict__ out_w,
                           float* __restrict__ out_att) {
    __shared__ bf16 Kt[2][TR * NA];
    const int tid = threadIdx.x;
    const int lane = tid & 63, w = tid >> 6;
    const int b = blockIdx.z, t0 = blockIdx.x * 64, sc = blockIdx.y;
    const int c = lane & 15, g = lane >> 4;
    const int trow = t0 + w * 16 + c;

    bf16x8 qf[4];
    const bf16* qrow = QK + (size_t)(b * NT + trow) * 256;
#pragma unroll
    for (int ks = 0; ks < 4; ++ks) qf[ks] = *(const bf16x8*)(qrow + ks * 32 + g * 8);

    float L = 0.f, W = 0.f;
#pragma unroll
    for (int ch = 0; ch < NCH; ++ch) {
        L += pl[ch * (NB * NT) + b * NT + trow];
        W += pw[ch * (NB * NT) + b * NT + trow];
    }
    const float lrow = 1.f / L;
    if (sc == 0 && g == 0) out_w[b * NT + trow] = W * lrow;

    const int sr0 = w * 2;
    const int lr = lane >> 4, cc = lane & 15;
    const bf16* kch = QK + (size_t)(b * NT + sc * SCH) * 256 + NA;

#pragma unroll
    for (int i = 0; i < 2; ++i) {
        const int r = (sr0 + i) * 4 + lr;
        gll16(kch + (size_t)r * 256 + ((cc ^ (r & 7)) * 8),
              (char*)Kt[0] + (sr0 + i) * 1024);
    }
    __syncthreads();

    float* orow = out_att + (size_t)(b * NT + trow) * NT;

    for (int tt = 0; tt < SCH / TR; ++tt) {
        if (tt + 1 < SCH / TR) {
#pragma unroll
            for (int i = 0; i < 2; ++i) {
                const int r = (sr0 + i) * 4 + lr;
                gll16(kch + (size_t)((tt + 1) * TR + r) * 256 + ((cc ^ (r & 7)) * 8),
                      (char*)Kt[(tt + 1) & 1] + (sr0 + i) * 1024);
            }
        }

        const char* kt = (const char*)Kt[tt & 1];
        const int s0 = sc * SCH + tt * TR;
#pragma unroll
        for (int ns = 0; ns < 2; ++ns) {
            f32x4 acc = f32x4{0.f, 0.f, 0.f, 0.f};
            const int rr = ns * 16 + c;
            const int rsw = (rr & 7) << 4;
#pragma unroll
            for (int ks = 0; ks < 4; ++ks) {
                const bf16x8 afr = *(const bf16x8*)(kt + rr * 256 +
                                                    ((ks * 64 + g * 16) ^ rsw));
                acc = __builtin_amdgcn_mfma_f32_16x16x32_bf16(afr, qf[ks], acc, 0, 0, 0);
            }
            f32x4 w4;
#pragma unroll
            for (int jj = 0; jj < 4; ++jj)
                w4[jj] = __expf(acc[jj] * SCALE) * lrow;
            *(f32x4*)(orow + s0 + ns * 16 + g * 4) = w4;
        }
        __syncthreads();
    }
}

// ---------------------------------------------------------------------------
extern "C" void kernel_launch(void* const* d_in, const int* in_sizes, int n_in,
                              void* d_out, int out_size, void* d_ws, size_t ws_size,
                              hipStream_t stream) {
    const float* x  = (const float*)d_in[0];
    const float* Wq = (const float*)d_in[1];
    const float* bq = (const float*)d_in[2];
    const float* Wk = (const float*)d_in[3];
    const float* bk = (const float*)d_in[4];
    const float* Wv = (const float*)d_in[5];
    const float* bv = (const float*)d_in[6];

    float* out_w   = (float*)d_out;            // [B,T,1] = 32768
    float* out_att = (float*)d_out + NB * NT;  // [B,T,T]

    char* ws = (char*)d_ws;
    bf16*  WT = (bf16*)ws;                       // 262144 B
    float* V  = (float*)(ws + 262144);           // 131072 B
    bf16*  QK = (bf16*)(ws + 393216);            // 16 MB
    float* pl = (float*)(ws + 17170432);         // 512 KB
    float* pw = (float*)(ws + 17694720);         // 512 KB

    prep_wt<<<dim3(256), dim3(256), 0, stream>>>(Wq, Wk, WT);
    norm_proj<<<dim3((NB * NT) / 16), dim3(256), 0, stream>>>(x, Wv, bv, WT, bq, bk, QK, V);
    attn_pass1<<<dim3(NT / 64, NCH, NB), dim3(256), 0, stream>>>(QK, V, pl, pw);
    attn_pass2<<<dim3(NT / 64, NCH, NB), dim3(256), 0, stream>>>(QK, pl, pw, out_w, out_att);
}